// Round 1
// 483.256 us; speedup vs baseline: 1.3176x; 1.3176x over previous
//
#include <hip/hip_runtime.h>
#include <stdint.h>
#include <stddef.h>

// ---------------------------------------------------------------------------
// Attention_7284264534326  (B=8, S=2048, D=1024). fp32 tensors, int32 mask,
// fp32 output.
//   q = (x1@wq)*D^-0.5 ; k = x2@wk ; v = x2@wv
//   a = softmax(q@k^T + mask*(-1e9)) ; y = relu(a@v) ; out = y@wo
// R7: replace the m97-style 128^2 2-barrier GEMM (measured 613 TF on PV,
// MfmaUtil 25%, conflict=0 -> structure-bound) with the 256^2 8-phase
// counted-vmcnt template (m194-m204):
//   - 512 thr / 8 waves (2M x 4N), BM=BN=256, BK=64, 2 K-tiles per iter.
//   - LDS 128 KiB: 2 buf x {A: 2x[128][64], B: 2x[128][64]} bf16,
//     XOR-swizzled 16B slots (slot ^= row&7); staged via global_load_lds
//     width-16 with inverse-swizzled per-lane GLOBAL source (LDS linear).
//   - per phase: {ds_read subtile || 1 half-tile stage} -> s_barrier ->
//     lgkmcnt(0) -> setprio(1) 16xMFMA setprio(0) -> s_barrier.
//   - vmcnt(4) only at phases 3 and 7 (2 half-tiles stay in flight across
//     barriers); vmcnt(0) only in the peeled final iteration.
// Stage/read hazard ledger (steady state, tiles T=2i,T+1; buf = tile&1):
//   ph0 stage (T+1).A0   last read of region: prev ph7  (>=1 bar + lgkm0)
//   ph1 stage (T+1).A1   prev ph7
//   ph2 stage (T+2).B0   ph0 (loadB)
//   ph3 stage (T+2).B1   ph0            vmcnt(4): newest 4 = ph2/ph3 loads,
//                                       forces (T+1).A* landed before ph4
//   ph4 stage (T+2).A0   ph3 (loadA q3)
//   ph5 stage (T+2).A1   ph3
//   ph6 stage (T+3).B0   ph4 (loadB)
//   ph7 stage (T+3).B1   ph4            vmcnt(4): forces (T+2).* landed
// K-accumulation order identical to R6 -> numerics unchanged.
// ---------------------------------------------------------------------------

typedef __bf16 bf16x8 __attribute__((ext_vector_type(8)));
typedef float  floatx4 __attribute__((ext_vector_type(4)));

__device__ __forceinline__ unsigned short f2bf(float f) {
    unsigned u = __float_as_uint(f);
    return (unsigned short)((u + 0x7FFFu + ((u >> 16) & 1u)) >> 16);  // RNE
}
__device__ __forceinline__ float bf2f(unsigned short h) {
    return __uint_as_float(((unsigned)h) << 16);
}

__device__ __forceinline__ void async16(const void* g, void* l) {
    __builtin_amdgcn_global_load_lds(
        (const __attribute__((address_space(1))) unsigned int*)g,
        (__attribute__((address_space(3))) unsigned int*)l, 16, 0, 0);
}

// ---------------------------------------------------------------------------
// fp32 -> bf16, n % 2048 == 0
// ---------------------------------------------------------------------------
__global__ __launch_bounds__(256) void cvt_bf16(
    const float* __restrict__ in, unsigned short* __restrict__ out, long long n)
{
    long long i8 = ((long long)blockIdx.x * 256 + threadIdx.x) * 8;
    if (i8 >= n) return;
    float4 a = *(const float4*)(in + i8);
    float4 b = *(const float4*)(in + i8 + 4);
    union { uint4 u; unsigned short h[8]; } o;
    o.h[0] = f2bf(a.x); o.h[1] = f2bf(a.y); o.h[2] = f2bf(a.z); o.h[3] = f2bf(a.w);
    o.h[4] = f2bf(b.x); o.h[5] = f2bf(b.y); o.h[6] = f2bf(b.z); o.h[7] = f2bf(b.w);
    *(uint4*)(out + i8) = o.u;
}

// ---------------------------------------------------------------------------
// fp32 [rows][cols] -> bf16 transposed out[c][r].  rows,cols % 32 == 0.
// ---------------------------------------------------------------------------
__global__ __launch_bounds__(256) void cvt_transpose_w(
    const float* __restrict__ in, unsigned short* __restrict__ out,
    int rows, int cols)
{
    __shared__ unsigned short tile[32][33];
    const int cbase = blockIdx.x * 32;
    const int rbase = blockIdx.y * 32;
#pragma unroll
    for (int i = 0; i < 4; i++) {
        int r = rbase + threadIdx.y + i * 8;
        tile[threadIdx.y + i * 8][threadIdx.x] =
            f2bf(in[(size_t)r * cols + (cbase + threadIdx.x)]);
    }
    __syncthreads();
#pragma unroll
    for (int i = 0; i < 4; i++) {
        int r = cbase + threadIdx.y + i * 8;
        out[(size_t)r * rows + (rbase + threadIdx.x)] =
            tile[threadIdx.x][threadIdx.y + i * 8];
    }
}

// ---------------------------------------------------------------------------
// C[m][n] = scale * sum_k A[m][k] * B[n][k]  (optional relu).
// A,B bf16; C bf16 (F32OUT=0) or fp32 (F32OUT=1).
// 256x256 tile, BK=64, 512 threads (8 waves, 2Mx4N), 8-phase schedule.
// M,N % 256 == 0, K % 128 == 0.
// 1-D grid of gx*gy*gz blocks; decode:
//   gz>1 : bz = id%gz (batch->XCD), 4x4 supertiles (gx%4==0, gy%4==0)
//   gz==1, gy%8==0: XCD m-banding; else plain row-major.
// ---------------------------------------------------------------------------
#define MFMA16(a, b, c) __builtin_amdgcn_mfma_f32_16x16x32_bf16(a, b, c, 0, 0, 0)
#define BARF()  { __builtin_amdgcn_s_barrier(); asm volatile("" ::: "memory"); }
#define LGKM0() asm volatile("s_waitcnt lgkmcnt(0)" ::: "memory")
#define VMC(N)  asm volatile("s_waitcnt vmcnt(" #N ")" ::: "memory")

template <int RELU, int F32OUT>
__global__ __launch_bounds__(512, 2) void gemm_bt(
    const unsigned short* __restrict__ A,
    const unsigned short* __restrict__ B,
    void* __restrict__ Cv,
    int K, int lda, int ldb, int ldc,
    long long sA, long long sB, long long sC,
    float scale, int gx, int gy, int gz)
{
    __shared__ __align__(16) char lds[131072];

    const int t    = threadIdx.x;
    const int wave = t >> 6;
    const int lane = t & 63;

    // ---- block swizzle ----
    int id = blockIdx.x;
    int bz, bx, by;
    if (gz > 1) {
        bz = id % gz;                      // batch pinned to XCD (id%8)
        int tt  = id / gz;
        int stw = gx >> 2;
        int st  = tt >> 4, lt = tt & 15;   // 4x4 supertile
        bx = (st % stw) * 4 + (lt & 3);
        by = (st / stw) * 4 + (lt >> 2);
    } else if ((gy & 7) == 0) {
        bz = 0;
        int band = gy >> 3;
        int q = id >> 3, x7 = id & 7;      // XCD x7 gets contiguous m-band
        by = x7 * band + q / gx;
        bx = q % gx;
    } else {
        bz = 0; bx = id % gx; by = id / gx;
    }

    A += (long long)bz * sA;
    B += (long long)bz * sB;

    const int m0 = by * 256;
    const int n0 = bx * 256;
    const int wm = (wave >> 2) * 128;      // 2 M-waves
    const int wn = (wave & 3) * 64;        // 4 N-waves
    const int fr = lane & 15;
    const int fj = lane >> 4;

    // ---- fragment read addressing (byte offsets, XOR-swizzled slots) ----
    // lds regions (16384 B each): buf*65536 + {A0=0, A1=1, B0=2, B1=3}*16384
    // data (row r, 8-elem slot s) stored at slot s ^ (r&7)
    const int slotX0 = ((fj    ) ^ (fr & 7)) << 4;   // k-half 0
    const int slotX1 = ((fj + 4) ^ (fr & 7)) << 4;   // k-half 1
    const int aBase = (wm >> 7) * 16384 + fr * 128;
    const int bBase = 32768 + (wn >> 7) * 16384 + (wn & 64) * 128 + fr * 128;

    // ---- staging source (inverse swizzle; LDS dest is linear) ----
    const int off0 = wave * 1024 + lane * 16;            // issue-0 LDS offset
    const int r0   = off0 >> 7;                          // row 0..63
    const int c0   = (((off0 >> 4) & 7) ^ (r0 & 7)) << 3;// element col
    const unsigned short* Ag = A + (size_t)(m0 + r0) * lda + c0;
    const unsigned short* Bg = B + (size_t)(n0 + r0) * ldb + c0;
    char* ldsW = lds + wave * 1024;                      // wave-uniform base

#define STAGE_A(tile, h) { \
    const unsigned short* g_ = Ag + (size_t)((h) * 128) * lda + (tile) * 64; \
    char* d_ = ldsW + ((tile) & 1) * 65536 + (h) * 16384; \
    async16(g_, d_); \
    async16(g_ + (size_t)64 * lda, d_ + 8192); }
#define STAGE_B(tile, h) { \
    const unsigned short* g_ = Bg + (size_t)((h) * 128) * ldb + (tile) * 64; \
    char* d_ = ldsW + ((tile) & 1) * 65536 + 32768 + (h) * 16384; \
    async16(g_, d_); \
    async16(g_ + (size_t)64 * ldb, d_ + 8192); }

    bf16x8 af[2][2], bfv[4][2];
#define LOAD_B(buf) { \
    const char* p_ = lds + (buf) * 65536 + bBase; \
    bfv[0][0] = *(const bf16x8*)(p_ +    0 + slotX0); \
    bfv[0][1] = *(const bf16x8*)(p_ +    0 + slotX1); \
    bfv[1][0] = *(const bf16x8*)(p_ + 2048 + slotX0); \
    bfv[1][1] = *(const bf16x8*)(p_ + 2048 + slotX1); \
    bfv[2][0] = *(const bf16x8*)(p_ + 4096 + slotX0); \
    bfv[2][1] = *(const bf16x8*)(p_ + 4096 + slotX1); \
    bfv[3][0] = *(const bf16x8*)(p_ + 6144 + slotX0); \
    bfv[3][1] = *(const bf16x8*)(p_ + 6144 + slotX1); }
#define LOAD_A(buf, q) { \
    const char* p_ = lds + (buf) * 65536 + aBase + (q) * 4096; \
    af[0][0] = *(const bf16x8*)(p_ +    0 + slotX0); \
    af[0][1] = *(const bf16x8*)(p_ +    0 + slotX1); \
    af[1][0] = *(const bf16x8*)(p_ + 2048 + slotX0); \
    af[1][1] = *(const bf16x8*)(p_ + 2048 + slotX1); }
#define MFMAQ(q) { \
    __builtin_amdgcn_s_setprio(1); \
    acc[2*(q)  ][0] = MFMA16(af[0][0], bfv[0][0], acc[2*(q)  ][0]); \
    acc[2*(q)  ][0] = MFMA16(af[0][1], bfv[0][1], acc[2*(q)  ][0]); \
    acc[2*(q)  ][1] = MFMA16(af[0][0], bfv[1][0], acc[2*(q)  ][1]); \
    acc[2*(q)  ][1] = MFMA16(af[0][1], bfv[1][1], acc[2*(q)  ][1]); \
    acc[2*(q)  ][2] = MFMA16(af[0][0], bfv[2][0], acc[2*(q)  ][2]); \
    acc[2*(q)  ][2] = MFMA16(af[0][1], bfv[2][1], acc[2*(q)  ][2]); \
    acc[2*(q)  ][3] = MFMA16(af[0][0], bfv[3][0], acc[2*(q)  ][3]); \
    acc[2*(q)  ][3] = MFMA16(af[0][1], bfv[3][1], acc[2*(q)  ][3]); \
    acc[2*(q)+1][0] = MFMA16(af[1][0], bfv[0][0], acc[2*(q)+1][0]); \
    acc[2*(q)+1][0] = MFMA16(af[1][1], bfv[0][1], acc[2*(q)+1][0]); \
    acc[2*(q)+1][1] = MFMA16(af[1][0], bfv[1][0], acc[2*(q)+1][1]); \
    acc[2*(q)+1][1] = MFMA16(af[1][1], bfv[1][1], acc[2*(q)+1][1]); \
    acc[2*(q)+1][2] = MFMA16(af[1][0], bfv[2][0], acc[2*(q)+1][2]); \
    acc[2*(q)+1][2] = MFMA16(af[1][1], bfv[2][1], acc[2*(q)+1][2]); \
    acc[2*(q)+1][3] = MFMA16(af[1][0], bfv[3][0], acc[2*(q)+1][3]); \
    acc[2*(q)+1][3] = MFMA16(af[1][1], bfv[3][1], acc[2*(q)+1][3]); \
    __builtin_amdgcn_s_setprio(0); }

    floatx4 acc[8][4];
#pragma unroll
    for (int i = 0; i < 8; i++)
#pragma unroll
        for (int j = 0; j < 4; j++) acc[i][j] = floatx4{0.f, 0.f, 0.f, 0.f};

    // ---- prologue: tile0 full + tile1 B-halves (6 half-tiles, 12 loads) ----
    STAGE_A(0, 0); STAGE_A(0, 1); STAGE_B(0, 0); STAGE_B(0, 1);
    STAGE_B(1, 0); STAGE_B(1, 1);
    VMC(4);                                  // tile0 (oldest 8 loads) landed
    BARF();

    const int niter = K >> 7;                // 2 K-tiles (BK=64) per iter
    for (int it = 0; it < niter - 1; ++it) {
        const int T = 2 * it;
        // ---- tile T (buf0) ----
        LOAD_B(0); LOAD_A(0, 0); STAGE_A(T + 1, 0);
        BARF(); LGKM0(); MFMAQ(0); BARF();
        LOAD_A(0, 1); STAGE_A(T + 1, 1);
        BARF(); LGKM0(); MFMAQ(1); BARF();
        LOAD_A(0, 2); STAGE_B(T + 2, 0);
        BARF(); LGKM0(); MFMAQ(2); BARF();
        LOAD_A(0, 3); STAGE_B(T + 2, 1);
        BARF(); LGKM0(); MFMAQ(3); VMC(4); BARF();
        // ---- tile T+1 (buf1) ----
        LOAD_B(1); LOAD_A(1, 0); STAGE_A(T + 2, 0);
        BARF(); LGKM0(); MFMAQ(0); BARF();
        LOAD_A(1, 1); STAGE_A(T + 2, 1);
        BARF(); LGKM0(); MFMAQ(1); BARF();
        LOAD_A(1, 2); STAGE_B(T + 3, 0);
        BARF(); LGKM0(); MFMAQ(2); BARF();
        LOAD_A(1, 3); STAGE_B(T + 3, 1);
        BARF(); LGKM0(); MFMAQ(3); VMC(4); BARF();
    }
    {   // ---- peeled final iteration (no T+2/T+3; drain) ----
        const int T = 2 * (niter - 1);
        LOAD_B(0); LOAD_A(0, 0); STAGE_A(T + 1, 0);
        BARF(); LGKM0(); MFMAQ(0); BARF();
        LOAD_A(0, 1); STAGE_A(T + 1, 1);
        BARF(); LGKM0(); MFMAQ(1); BARF();
        LOAD_A(0, 2);
        BARF(); LGKM0(); MFMAQ(2); BARF();
        LOAD_A(0, 3);
        BARF(); LGKM0(); MFMAQ(3); VMC(0); BARF();
        LOAD_B(1); LOAD_A(1, 0);
        BARF(); LGKM0(); MFMAQ(0); BARF();
        LOAD_A(1, 1);
        BARF(); LGKM0(); MFMAQ(1); BARF();
        LOAD_A(1, 2);
        BARF(); LGKM0(); MFMAQ(2); BARF();
        LOAD_A(1, 3);
        BARF(); LGKM0(); MFMAQ(3); BARF();
    }

    // C/D layout (m89-verified): col = lane&15, row = (lane>>4)*4 + r
    const int er = (lane >> 4) * 4;
    const int ec = lane & 15;
    if (F32OUT) {
        float* C = (float*)Cv + (long long)bz * sC;
#pragma unroll
        for (int i = 0; i < 8; i++)
#pragma unroll
            for (int j = 0; j < 4; j++)
#pragma unroll
                for (int r = 0; r < 4; r++) {
                    float v = acc[i][j][r] * scale;
                    if (RELU) v = fmaxf(v, 0.f);
                    C[(size_t)(m0 + wm + i * 16 + er + r) * ldc
                      + (n0 + wn + j * 16 + ec)] = v;
                }
    } else {
        unsigned short* C = (unsigned short*)Cv + (long long)bz * sC;
#pragma unroll
        for (int i = 0; i < 8; i++)
#pragma unroll
            for (int j = 0; j < 4; j++)
#pragma unroll
                for (int r = 0; r < 4; r++) {
                    float v = acc[i][j][r] * scale;
                    if (RELU) v = fmaxf(v, 0.f);
                    C[(size_t)(m0 + wm + i * 16 + er + r) * ldc
                      + (n0 + wn + j * 16 + ec)] = f2bf(v);
                }
    }
#undef STAGE_A
#undef STAGE_B
#undef LOAD_A
#undef LOAD_B
#undef MFMAQ
}

// ---------------------------------------------------------------------------
// In-place masked softmax over bf16 rows (len Sk=2048), fp32 math.
// ---------------------------------------------------------------------------
__global__ __launch_bounds__(256) void softmax_rows(
    unsigned short* __restrict__ S, const int* __restrict__ mask,
    int b0, int Sq, int Sk)
{
    const int row = blockIdx.x;
    const int b   = b0 + row / Sq;
    unsigned short* p  = S + (size_t)row * Sk;
    const int*      mk = mask + (size_t)b * Sk;

    const int t    = threadIdx.x;
    const int wave = t >> 6;
    const int lane = t & 63;

    union { uint4 u; unsigned short h[8]; } lu;
    lu.u = *(const uint4*)(p + t * 8);
    int4 m0 = *(const int4*)(mk + t * 8);
    int4 m1 = *(const int4*)(mk + t * 8 + 4);
    int mi[8] = {m0.x, m0.y, m0.z, m0.w, m1.x, m1.y, m1.z, m1.w};

    float v[8];
    float mx = -3.0e38f;
#pragma unroll
    for (int j = 0; j < 8; j++) {
        v[j] = bf2f(lu.h[j]) + (float)mi[j] * (-1.0e9f);
        mx = fmaxf(mx, v[j]);
    }
#pragma unroll
    for (int o = 32; o > 0; o >>= 1) mx = fmaxf(mx, __shfl_xor(mx, o));

    __shared__ float red[4];
    if (lane == 0) red[wave] = mx;
    __syncthreads();
    mx = fmaxf(fmaxf(red[0], red[1]), fmaxf(red[2], red[3]));

    float sum = 0.f;
#pragma unroll
    for (int j = 0; j < 8; j++) {
        v[j] = __expf(v[j] - mx);
        sum += v[j];
    }
#pragma unroll
    for (int o = 32; o > 0; o >>= 1) sum += __shfl_xor(sum, o);
    __syncthreads();
    if (lane == 0) red[wave] = sum;
    __syncthreads();
    sum = red[0] + red[1] + red[2] + red[3];

    const float inv = 1.0f / sum;
#pragma unroll
    for (int j = 0; j < 8; j++) lu.h[j] = f2bf(v[j] * inv);
    *(uint4*)(p + t * 8) = lu.u;
}

// Diagnostic: future failure with absmax ~1.3 => "ws too small" branch fired.
__global__ void fill_one_f32(float* o, int n) {
    int i = blockIdx.x * 256 + threadIdx.x;
    if (i < n) o[i] = 1.0f;
}

// ---------------------------------------------------------------------------
extern "C" void kernel_launch(void* const* d_in, const int* in_sizes, int n_in,
                              void* d_out, int out_size, void* d_ws, size_t ws_size,
                              hipStream_t stream)
{
    const float* x1   = (const float*)d_in[0];
    const float* x2   = (const float*)d_in[1];
    const int*   mask = (const int*)d_in[2];
    const float* wq   = (const float*)d_in[3];
    const float* wk   = (const float*)d_in[4];
    const float* wv   = (const float*)d_in[5];
    const float* wo   = (const float*)d_in[6];
    float*       out  = (float*)d_out;

    const int S = 2048, D = 1024, Btot = 8;

    // ws bf16 elems = 4*D*D + nb*(5*S*D + S*S):  8MB + nb*28MB bytes
    const size_t WT = (size_t)4 * D * D;
    const size_t PB = (size_t)5 * S * D + (size_t)S * S;
    const size_t avail = ws_size / 2;
    int nb = 0;
    if      (WT + 8 * PB <= avail) nb = 8;
    else if (WT + 4 * PB <= avail) nb = 4;
    else if (WT + 2 * PB <= avail) nb = 2;
    else if (WT + 1 * PB <= avail) nb = 1;
    if (nb == 0) {
        fill_one_f32<<<(out_size + 255) / 256, 256, 0, stream>>>(out, out_size);
        return;
    }

    unsigned short* wqT = (unsigned short*)d_ws;
    unsigned short* wkT = wqT + (size_t)D * D;
    unsigned short* wvT = wkT + (size_t)D * D;
    unsigned short* woT = wvT + (size_t)D * D;
    unsigned short* x1b = woT + (size_t)D * D;              // nb*S x D  bf16
    unsigned short* x2b = x1b + (size_t)nb * S * D;         // nb*S x D
    unsigned short* q   = x2b + (size_t)nb * S * D;         // nb*S x D
    unsigned short* kk  = q   + (size_t)nb * S * D;         // nb*S x D
    unsigned short* vT  = kk  + (size_t)nb * S * D;         // D x nb*S
    unsigned short* sc  = vT  + (size_t)nb * S * D;         // nb x S x S
    unsigned short* y   = q;                                // alias (q dead)

    dim3 tb(32, 8);
    cvt_transpose_w<<<dim3(32, 32), tb, 0, stream>>>(wq, wqT, D, D);
    cvt_transpose_w<<<dim3(32, 32), tb, 0, stream>>>(wk, wkT, D, D);
    cvt_transpose_w<<<dim3(32, 32), tb, 0, stream>>>(wv, wvT, D, D);
    cvt_transpose_w<<<dim3(32, 32), tb, 0, stream>>>(wo, woT, D, D);

    const int BSc = nb * S;                                 // rows per chunk
    const int MTb = BSc / 256;                              // 256-wide m-tiles
    const long long NE = (long long)BSc * D;                // elems per chunk
    for (int c0 = 0; c0 < Btot; c0 += nb) {
        const float* x1c = x1 + (size_t)c0 * S * D;
        const float* x2c = x2 + (size_t)c0 * S * D;

        cvt_bf16<<<(int)(NE / 2048), 256, 0, stream>>>(x1c, x1b, NE);
        cvt_bf16<<<(int)(NE / 2048), 256, 0, stream>>>(x2c, x2b, NE);

        // q = x1b @ wqT^T * D^-0.5     (gx=4 n-tiles, gy=MTb m-tiles)
        gemm_bt<0, 0><<<4 * MTb, 512, 0, stream>>>(
            x1b, wqT, q, D, D, D, D, 0, 0, 0, 0.03125f, 4, MTb, 1);
        // k = x2b @ wkT^T
        gemm_bt<0, 0><<<4 * MTb, 512, 0, stream>>>(
            x2b, wkT, kk, D, D, D, D, 0, 0, 0, 1.0f, 4, MTb, 1);
        // vT[e][s] = sum_d wvT[e][d] * x2b[s][d]   (D x BSc; gx=MTb, gy=4)
        gemm_bt<0, 0><<<MTb * 4, 512, 0, stream>>>(
            wvT, x2b, vT, D, D, D, BSc, 0, 0, 0, 1.0f, MTb, 4, 1);

        // scores[z] = q_z @ k_z^T   (gx=8, gy=8, gz=nb)
        gemm_bt<0, 0><<<8 * 8 * nb, 512, 0, stream>>>(
            q, kk, sc, D, D, D, S,
            (long long)S * D, (long long)S * D, (long long)S * S, 1.0f,
            8, 8, nb);

        // masked softmax in place
        softmax_rows<<<BSc, 256, 0, stream>>>(sc, mask, c0, S, S);

        // y[z] = relu(P_z @ v_z) : B^T = vT (batch cols z*S, ldb=BSc)
        gemm_bt<1, 0><<<4 * 8 * nb, 512, 0, stream>>>(
            sc, vT, y, S, S, BSc, D,
            (long long)S * S, (long long)S, (long long)S * D, 1.0f,
            4, 8, nb);

        // out_chunk = y @ woT^T   (fp32 output)
        gemm_bt<0, 1><<<4 * MTb, 512, 0, stream>>>(
            y, woT, out + (size_t)c0 * S * D, D, D, D, D, 0, 0, 0, 1.0f,
            4, MTb, 1);
    }
}

// Round 2
// 471.569 us; speedup vs baseline: 1.3503x; 1.0248x over previous
//
#include <hip/hip_runtime.h>
#include <stdint.h>
#include <stddef.h>

// ---------------------------------------------------------------------------
// Attention_7284264534326  (B=8, S=2048, D=1024). fp32 tensors, int32 mask,
// fp32 output.
//   q = (x1@wq)*D^-0.5 ; k = x2@wk ; v = x2@wv
//   a = softmax(q@k^T + mask*(-1e9)) ; y = relu(a@v) ; out = y@wo
// R8: keep the R7 256^2 8-phase counted-vmcnt GEMM core (954 TF @K=1024,
// above the m248 reference of 848 for this regime). Attack dispatch-count
// overhead instead (~120us unaccounted across 13 launches):
//   - q/k/vT GEMMs are independent -> ONE 768-block dispatch (3 descriptors,
//     single core instance, wave-uniform select; tails overlap).
//   - 4 weight transposes -> one z-indexed launch.
//   - 2 fp32->bf16 converts -> one z-indexed launch.
// 13 -> 7 dispatches per run. GEMM inner loop unchanged (bit-identical math).
// ---------------------------------------------------------------------------

typedef __bf16 bf16x8 __attribute__((ext_vector_type(8)));
typedef float  floatx4 __attribute__((ext_vector_type(4)));

__device__ __forceinline__ unsigned short f2bf(float f) {
    unsigned u = __float_as_uint(f);
    return (unsigned short)((u + 0x7FFFu + ((u >> 16) & 1u)) >> 16);  // RNE
}
__device__ __forceinline__ float bf2f(unsigned short h) {
    return __uint_as_float(((unsigned)h) << 16);
}

__device__ __forceinline__ void async16(const void* g, void* l) {
    __builtin_amdgcn_global_load_lds(
        (const __attribute__((address_space(1))) unsigned int*)g,
        (__attribute__((address_space(3))) unsigned int*)l, 16, 0, 0);
}

// ---------------------------------------------------------------------------
// fp32 -> bf16, n % 2048 == 0.  blockIdx.y selects source {a,b}; dst is
// contiguous: out + y*n.
// ---------------------------------------------------------------------------
__global__ __launch_bounds__(256) void cvt_bf16_2(
    const float* __restrict__ a, const float* __restrict__ b,
    unsigned short* __restrict__ out, long long n)
{
    const float* in = blockIdx.y ? b : a;
    unsigned short* o = out + (size_t)blockIdx.y * n;
    long long i8 = ((long long)blockIdx.x * 256 + threadIdx.x) * 8;
    if (i8 >= n) return;
    float4 va = *(const float4*)(in + i8);
    float4 vb = *(const float4*)(in + i8 + 4);
    union { uint4 u; unsigned short h[8]; } ov;
    ov.h[0] = f2bf(va.x); ov.h[1] = f2bf(va.y); ov.h[2] = f2bf(va.z); ov.h[3] = f2bf(va.w);
    ov.h[4] = f2bf(vb.x); ov.h[5] = f2bf(vb.y); ov.h[6] = f2bf(vb.z); ov.h[7] = f2bf(vb.w);
    *(uint4*)(o + i8) = ov.u;
}

// ---------------------------------------------------------------------------
// fp32 [rows][cols] -> bf16 transposed out[c][r], 4 matrices (z-indexed).
// rows,cols % 32 == 0.  dsts contiguous at out + z*rows*cols.
// ---------------------------------------------------------------------------
__global__ __launch_bounds__(256) void cvt_transpose_w4(
    const float* __restrict__ w0, const float* __restrict__ w1,
    const float* __restrict__ w2, const float* __restrict__ w3,
    unsigned short* __restrict__ out, int rows, int cols)
{
    const int z = blockIdx.z;
    const float* in = (z == 0) ? w0 : (z == 1) ? w1 : (z == 2) ? w2 : w3;
    unsigned short* o = out + (size_t)z * rows * cols;

    __shared__ unsigned short tile[32][33];
    const int cbase = blockIdx.x * 32;
    const int rbase = blockIdx.y * 32;
#pragma unroll
    for (int i = 0; i < 4; i++) {
        int r = rbase + threadIdx.y + i * 8;
        tile[threadIdx.y + i * 8][threadIdx.x] =
            f2bf(in[(size_t)r * cols + (cbase + threadIdx.x)]);
    }
    __syncthreads();
#pragma unroll
    for (int i = 0; i < 4; i++) {
        int r = cbase + threadIdx.y + i * 8;
        o[(size_t)r * rows + (rbase + threadIdx.x)] =
            tile[threadIdx.x][threadIdx.y + i * 8];
    }
}

// ---------------------------------------------------------------------------
// C[m][n] = scale * sum_k A[m][k] * B[n][k]  (optional relu).
// A,B bf16; C bf16 (F32OUT=0) or fp32 (F32OUT=1).
// 256x256 tile, BK=64, 512 threads (8 waves, 2Mx4N), 8-phase schedule
// (m194-m204 template). M,N % 256 == 0, K % 128 == 0.
// Block decode from local id:
//   gz>1 : bz = id%gz (batch->XCD), 4x4 supertiles (gx%4==0)
//   gz==1, gy%8==0: XCD m-banding; else plain row-major.
// Stage/read hazard ledger: see R7 header (unchanged).
// ---------------------------------------------------------------------------
#define MFMA16(a, b, c) __builtin_amdgcn_mfma_f32_16x16x32_bf16(a, b, c, 0, 0, 0)
#define BARF()  { __builtin_amdgcn_s_barrier(); asm volatile("" ::: "memory"); }
#define LGKM0() asm volatile("s_waitcnt lgkmcnt(0)" ::: "memory")
#define VMC(N)  asm volatile("s_waitcnt vmcnt(" #N ")" ::: "memory")

template <int RELU, int F32OUT>
__device__ __forceinline__ void gemm_core(
    const unsigned short* A, const unsigned short* B, void* Cv,
    int K, int lda, int ldb, int ldc,
    long long sA, long long sB, long long sC,
    float scale, int gx, int gy, int gz, int id, char* lds)
{
    const int t    = threadIdx.x;
    const int wave = t >> 6;
    const int lane = t & 63;

    // ---- block swizzle ----
    int bz, bx, by;
    if (gz > 1) {
        bz = id % gz;                      // batch pinned to XCD (id%8)
        int tt  = id / gz;
        int stw = gx >> 2;
        int st  = tt >> 4, lt = tt & 15;   // 4x4 supertile
        bx = (st % stw) * 4 + (lt & 3);
        by = (st / stw) * 4 + (lt >> 2);
    } else if ((gy & 7) == 0) {
        bz = 0;
        int band = gy >> 3;
        int q = id >> 3, x7 = id & 7;      // XCD x7 gets contiguous m-band
        by = x7 * band + q / gx;
        bx = q % gx;
    } else {
        bz = 0; bx = id % gx; by = id / gx;
    }

    A += (long long)bz * sA;
    B += (long long)bz * sB;

    const int m0 = by * 256;
    const int n0 = bx * 256;
    const int wm = (wave >> 2) * 128;      // 2 M-waves
    const int wn = (wave & 3) * 64;        // 4 N-waves
    const int fr = lane & 15;
    const int fj = lane >> 4;

    // ---- fragment read addressing (byte offsets, XOR-swizzled slots) ----
    // lds regions (16384 B each): buf*65536 + {A0=0, A1=1, B0=2, B1=3}*16384
    // data (row r, 8-elem slot s) stored at slot s ^ (r&7)
    const int slotX0 = ((fj    ) ^ (fr & 7)) << 4;   // k-half 0
    const int slotX1 = ((fj + 4) ^ (fr & 7)) << 4;   // k-half 1
    const int aBase = (wm >> 7) * 16384 + fr * 128;
    const int bBase = 32768 + (wn >> 7) * 16384 + (wn & 64) * 128 + fr * 128;

    // ---- staging source (inverse swizzle; LDS dest is linear) ----
    const int off0 = wave * 1024 + lane * 16;            // issue-0 LDS offset
    const int r0   = off0 >> 7;                          // row 0..63
    const int c0   = (((off0 >> 4) & 7) ^ (r0 & 7)) << 3;// element col
    const unsigned short* Ag = A + (size_t)(m0 + r0) * lda + c0;
    const unsigned short* Bg = B + (size_t)(n0 + r0) * ldb + c0;
    char* ldsW = lds + wave * 1024;                      // wave-uniform base

#define STAGE_A(tile, h) { \
    const unsigned short* g_ = Ag + (size_t)((h) * 128) * lda + (tile) * 64; \
    char* d_ = ldsW + ((tile) & 1) * 65536 + (h) * 16384; \
    async16(g_, d_); \
    async16(g_ + (size_t)64 * lda, d_ + 8192); }
#define STAGE_B(tile, h) { \
    const unsigned short* g_ = Bg + (size_t)((h) * 128) * ldb + (tile) * 64; \
    char* d_ = ldsW + ((tile) & 1) * 65536 + 32768 + (h) * 16384; \
    async16(g_, d_); \
    async16(g_ + (size_t)64 * ldb, d_ + 8192); }

    bf16x8 af[2][2], bfv[4][2];
#define LOAD_B(buf) { \
    const char* p_ = lds + (buf) * 65536 + bBase; \
    bfv[0][0] = *(const bf16x8*)(p_ +    0 + slotX0); \
    bfv[0][1] = *(const bf16x8*)(p_ +    0 + slotX1); \
    bfv[1][0] = *(const bf16x8*)(p_ + 2048 + slotX0); \
    bfv[1][1] = *(const bf16x8*)(p_ + 2048 + slotX1); \
    bfv[2][0] = *(const bf16x8*)(p_ + 4096 + slotX0); \
    bfv[2][1] = *(const bf16x8*)(p_ + 4096 + slotX1); \
    bfv[3][0] = *(const bf16x8*)(p_ + 6144 + slotX0); \
    bfv[3][1] = *(const bf16x8*)(p_ + 6144 + slotX1); }
#define LOAD_A(buf, q) { \
    const char* p_ = lds + (buf) * 65536 + aBase + (q) * 4096; \
    af[0][0] = *(const bf16x8*)(p_ +    0 + slotX0); \
    af[0][1] = *(const bf16x8*)(p_ +    0 + slotX1); \
    af[1][0] = *(const bf16x8*)(p_ + 2048 + slotX0); \
    af[1][1] = *(const bf16x8*)(p_ + 2048 + slotX1); }
#define MFMAQ(q) { \
    __builtin_amdgcn_s_setprio(1); \
    acc[2*(q)  ][0] = MFMA16(af[0][0], bfv[0][0], acc[2*(q)  ][0]); \
    acc[2*(q)  ][0] = MFMA16(af[0][1], bfv[0][1], acc[2*(q)  ][0]); \
    acc[2*(q)  ][1] = MFMA16(af[0][0], bfv[1][0], acc[2*(q)  ][1]); \
    acc[2*(q)  ][1] = MFMA16(af[0][1], bfv[1][1], acc[2*(q)  ][1]); \
    acc[2*(q)  ][2] = MFMA16(af[0][0], bfv[2][0], acc[2*(q)  ][2]); \
    acc[2*(q)  ][2] = MFMA16(af[0][1], bfv[2][1], acc[2*(q)  ][2]); \
    acc[2*(q)  ][3] = MFMA16(af[0][0], bfv[3][0], acc[2*(q)  ][3]); \
    acc[2*(q)  ][3] = MFMA16(af[0][1], bfv[3][1], acc[2*(q)  ][3]); \
    acc[2*(q)+1][0] = MFMA16(af[1][0], bfv[0][0], acc[2*(q)+1][0]); \
    acc[2*(q)+1][0] = MFMA16(af[1][1], bfv[0][1], acc[2*(q)+1][0]); \
    acc[2*(q)+1][1] = MFMA16(af[1][0], bfv[1][0], acc[2*(q)+1][1]); \
    acc[2*(q)+1][1] = MFMA16(af[1][1], bfv[1][1], acc[2*(q)+1][1]); \
    acc[2*(q)+1][2] = MFMA16(af[1][0], bfv[2][0], acc[2*(q)+1][2]); \
    acc[2*(q)+1][2] = MFMA16(af[1][1], bfv[2][1], acc[2*(q)+1][2]); \
    acc[2*(q)+1][3] = MFMA16(af[1][0], bfv[3][0], acc[2*(q)+1][3]); \
    acc[2*(q)+1][3] = MFMA16(af[1][1], bfv[3][1], acc[2*(q)+1][3]); \
    __builtin_amdgcn_s_setprio(0); }

    floatx4 acc[8][4];
#pragma unroll
    for (int i = 0; i < 8; i++)
#pragma unroll
        for (int j = 0; j < 4; j++) acc[i][j] = floatx4{0.f, 0.f, 0.f, 0.f};

    // ---- prologue: tile0 full + tile1 B-halves (6 half-tiles, 12 loads) ----
    STAGE_A(0, 0); STAGE_A(0, 1); STAGE_B(0, 0); STAGE_B(0, 1);
    STAGE_B(1, 0); STAGE_B(1, 1);
    VMC(4);                                  // tile0 (oldest 8 loads) landed
    BARF();

    const int niter = K >> 7;                // 2 K-tiles (BK=64) per iter
    for (int it = 0; it < niter - 1; ++it) {
        const int T = 2 * it;
        // ---- tile T (buf0) ----
        LOAD_B(0); LOAD_A(0, 0); STAGE_A(T + 1, 0);
        BARF(); LGKM0(); MFMAQ(0); BARF();
        LOAD_A(0, 1); STAGE_A(T + 1, 1);
        BARF(); LGKM0(); MFMAQ(1); BARF();
        LOAD_A(0, 2); STAGE_B(T + 2, 0);
        BARF(); LGKM0(); MFMAQ(2); BARF();
        LOAD_A(0, 3); STAGE_B(T + 2, 1);
        BARF(); LGKM0(); MFMAQ(3); VMC(4); BARF();
        // ---- tile T+1 (buf1) ----
        LOAD_B(1); LOAD_A(1, 0); STAGE_A(T + 2, 0);
        BARF(); LGKM0(); MFMAQ(0); BARF();
        LOAD_A(1, 1); STAGE_A(T + 2, 1);
        BARF(); LGKM0(); MFMAQ(1); BARF();
        LOAD_A(1, 2); STAGE_B(T + 3, 0);
        BARF(); LGKM0(); MFMAQ(2); BARF();
        LOAD_A(1, 3); STAGE_B(T + 3, 1);
        BARF(); LGKM0(); MFMAQ(3); VMC(4); BARF();
    }
    {   // ---- peeled final iteration (no T+2/T+3; drain) ----
        const int T = 2 * (niter - 1);
        LOAD_B(0); LOAD_A(0, 0); STAGE_A(T + 1, 0);
        BARF(); LGKM0(); MFMAQ(0); BARF();
        LOAD_A(0, 1); STAGE_A(T + 1, 1);
        BARF(); LGKM0(); MFMAQ(1); BARF();
        LOAD_A(0, 2);
        BARF(); LGKM0(); MFMAQ(2); BARF();
        LOAD_A(0, 3);
        BARF(); LGKM0(); MFMAQ(3); VMC(0); BARF();
        LOAD_B(1); LOAD_A(1, 0);
        BARF(); LGKM0(); MFMAQ(0); BARF();
        LOAD_A(1, 1);
        BARF(); LGKM0(); MFMAQ(1); BARF();
        LOAD_A(1, 2);
        BARF(); LGKM0(); MFMAQ(2); BARF();
        LOAD_A(1, 3);
        BARF(); LGKM0(); MFMAQ(3); BARF();
    }

    // C/D layout (m89-verified): col = lane&15, row = (lane>>4)*4 + r
    const int er = (lane >> 4) * 4;
    const int ec = lane & 15;
    if (F32OUT) {
        float* C = (float*)Cv + (long long)bz * sC;
#pragma unroll
        for (int i = 0; i < 8; i++)
#pragma unroll
            for (int j = 0; j < 4; j++)
#pragma unroll
                for (int r = 0; r < 4; r++) {
                    float v = acc[i][j][r] * scale;
                    if (RELU) v = fmaxf(v, 0.f);
                    C[(size_t)(m0 + wm + i * 16 + er + r) * ldc
                      + (n0 + wn + j * 16 + ec)] = v;
                }
    } else {
        unsigned short* C = (unsigned short*)Cv + (long long)bz * sC;
#pragma unroll
        for (int i = 0; i < 8; i++)
#pragma unroll
            for (int j = 0; j < 4; j++)
#pragma unroll
                for (int r = 0; r < 4; r++) {
                    float v = acc[i][j][r] * scale;
                    if (RELU) v = fmaxf(v, 0.f);
                    C[(size_t)(m0 + wm + i * 16 + er + r) * ldc
                      + (n0 + wn + j * 16 + ec)] = f2bf(v);
                }
    }
#undef STAGE_A
#undef STAGE_B
#undef LOAD_A
#undef LOAD_B
#undef MFMAQ
}

template <int RELU, int F32OUT>
__global__ __launch_bounds__(512, 2) void gemm_bt(
    const unsigned short* __restrict__ A,
    const unsigned short* __restrict__ B,
    void* __restrict__ Cv,
    int K, int lda, int ldb, int ldc,
    long long sA, long long sB, long long sC,
    float scale, int gx, int gy, int gz)
{
    __shared__ __align__(16) char lds[131072];
    gemm_core<RELU, F32OUT>(A, B, Cv, K, lda, ldb, ldc, sA, sB, sC,
                            scale, gx, gy, gz, blockIdx.x, lds);
}

// ---- 3-problem merged GEMM (independent problems, one dispatch) ----------
struct GemmDesc {
    const unsigned short* A;
    const unsigned short* B;
    void* C;
    int K, lda, ldb, ldc;
    long long sA, sB, sC;
    float scale;
    int gx, gy, gz, nblk;
};
struct GemmDesc3 { GemmDesc d[3]; };

__global__ __launch_bounds__(512, 2) void gemm_bt3(GemmDesc3 dd)
{
    __shared__ __align__(16) char lds[131072];
    int id = blockIdx.x;
    GemmDesc g = dd.d[0];
    if (id >= g.nblk) {
        id -= g.nblk; g = dd.d[1];
        if (id >= g.nblk) { id -= g.nblk; g = dd.d[2]; }
    }
    gemm_core<0, 0>(g.A, g.B, g.C, g.K, g.lda, g.ldb, g.ldc,
                    g.sA, g.sB, g.sC, g.scale, g.gx, g.gy, g.gz, id, lds);
}

// ---------------------------------------------------------------------------
// In-place masked softmax over bf16 rows (len Sk=2048), fp32 math.
// ---------------------------------------------------------------------------
__global__ __launch_bounds__(256) void softmax_rows(
    unsigned short* __restrict__ S, const int* __restrict__ mask,
    int b0, int Sq, int Sk)
{
    const int row = blockIdx.x;
    const int b   = b0 + row / Sq;
    unsigned short* p  = S + (size_t)row * Sk;
    const int*      mk = mask + (size_t)b * Sk;

    const int t    = threadIdx.x;
    const int wave = t >> 6;
    const int lane = t & 63;

    union { uint4 u; unsigned short h[8]; } lu;
    lu.u = *(const uint4*)(p + t * 8);
    int4 m0 = *(const int4*)(mk + t * 8);
    int4 m1 = *(const int4*)(mk + t * 8 + 4);
    int mi[8] = {m0.x, m0.y, m0.z, m0.w, m1.x, m1.y, m1.z, m1.w};

    float v[8];
    float mx = -3.0e38f;
#pragma unroll
    for (int j = 0; j < 8; j++) {
        v[j] = bf2f(lu.h[j]) + (float)mi[j] * (-1.0e9f);
        mx = fmaxf(mx, v[j]);
    }
#pragma unroll
    for (int o = 32; o > 0; o >>= 1) mx = fmaxf(mx, __shfl_xor(mx, o));

    __shared__ float red[4];
    if (lane == 0) red[wave] = mx;
    __syncthreads();
    mx = fmaxf(fmaxf(red[0], red[1]), fmaxf(red[2], red[3]));

    float sum = 0.f;
#pragma unroll
    for (int j = 0; j < 8; j++) {
        v[j] = __expf(v[j] - mx);
        sum += v[j];
    }
#pragma unroll
    for (int o = 32; o > 0; o >>= 1) sum += __shfl_xor(sum, o);
    __syncthreads();
    if (lane == 0) red[wave] = sum;
    __syncthreads();
    sum = red[0] + red[1] + red[2] + red[3];

    const float inv = 1.0f / sum;
#pragma unroll
    for (int j = 0; j < 8; j++) lu.h[j] = f2bf(v[j] * inv);
    *(uint4*)(p + t * 8) = lu.u;
}

// Diagnostic: future failure with absmax ~1.3 => "ws too small" branch fired.
__global__ void fill_one_f32(float* o, int n) {
    int i = blockIdx.x * 256 + threadIdx.x;
    if (i < n) o[i] = 1.0f;
}

// ---------------------------------------------------------------------------
extern "C" void kernel_launch(void* const* d_in, const int* in_sizes, int n_in,
                              void* d_out, int out_size, void* d_ws, size_t ws_size,
                              hipStream_t stream)
{
    const float* x1   = (const float*)d_in[0];
    const float* x2   = (const float*)d_in[1];
    const int*   mask = (const int*)d_in[2];
    const float* wq   = (const float*)d_in[3];
    const float* wk   = (const float*)d_in[4];
    const float* wv   = (const float*)d_in[5];
    const float* wo   = (const float*)d_in[6];
    float*       out  = (float*)d_out;

    const int S = 2048, D = 1024, Btot = 8;

    // ws bf16 elems = 4*D*D + nb*(5*S*D + S*S):  8MB + nb*28MB bytes
    const size_t WT = (size_t)4 * D * D;
    const size_t PB = (size_t)5 * S * D + (size_t)S * S;
    const size_t avail = ws_size / 2;
    int nb = 0;
    if      (WT + 8 * PB <= avail) nb = 8;
    else if (WT + 4 * PB <= avail) nb = 4;
    else if (WT + 2 * PB <= avail) nb = 2;
    else if (WT + 1 * PB <= avail) nb = 1;
    if (nb == 0) {
        fill_one_f32<<<(out_size + 255) / 256, 256, 0, stream>>>(out, out_size);
        return;
    }

    unsigned short* wqT = (unsigned short*)d_ws;
    unsigned short* wkT = wqT + (size_t)D * D;
    unsigned short* wvT = wkT + (size_t)D * D;
    unsigned short* woT = wvT + (size_t)D * D;
    unsigned short* x1b = woT + (size_t)D * D;              // nb*S x D  bf16
    unsigned short* x2b = x1b + (size_t)nb * S * D;         // nb*S x D
    unsigned short* q   = x2b + (size_t)nb * S * D;         // nb*S x D
    unsigned short* kk  = q   + (size_t)nb * S * D;         // nb*S x D
    unsigned short* vT  = kk  + (size_t)nb * S * D;         // D x nb*S
    unsigned short* sc  = vT  + (size_t)nb * S * D;         // nb x S x S
    unsigned short* y   = q;                                // alias (q dead)

    // all 4 weight transposes in one launch (dsts contiguous from wqT)
    cvt_transpose_w4<<<dim3(32, 32, 4), dim3(32, 8), 0, stream>>>(
        wq, wk, wv, wo, wqT, D, D);

    const int BSc = nb * S;                                 // rows per chunk
    const int MTb = BSc / 256;                              // 256-wide m-tiles
    const long long NE = (long long)BSc * D;                // elems per chunk
    for (int c0 = 0; c0 < Btot; c0 += nb) {
        const float* x1c = x1 + (size_t)c0 * S * D;
        const float* x2c = x2 + (size_t)c0 * S * D;

        // both converts in one launch (x1b,x2b contiguous)
        cvt_bf16_2<<<dim3((unsigned)(NE / 2048), 2), 256, 0, stream>>>(
            x1c, x2c, x1b, NE);

        // q/k/vT projections: 3 independent problems, one dispatch
        GemmDesc3 dd;
        // q = x1b @ wqT^T * D^-0.5
        dd.d[0] = {x1b, wqT, q, D, D, D, D, 0, 0, 0, 0.03125f, 4, MTb, 1, 4 * MTb};
        // k = x2b @ wkT^T
        dd.d[1] = {x2b, wkT, kk, D, D, D, D, 0, 0, 0, 1.0f, 4, MTb, 1, 4 * MTb};
        // vT[e][s] = sum_d wvT[e][d] * x2b[s][d]   (D x BSc)
        dd.d[2] = {wvT, x2b, vT, D, D, D, BSc, 0, 0, 0, 1.0f, MTb, 4, 1, MTb * 4};
        gemm_bt3<<<12 * MTb, 512, 0, stream>>>(dd);

        // scores[z] = q_z @ k_z^T   (gx=8, gy=8, gz=nb)
        gemm_bt<0, 0><<<8 * 8 * nb, 512, 0, stream>>>(
            q, kk, sc, D, D, D, S,
            (long long)S * D, (long long)S * D, (long long)S * S, 1.0f,
            8, 8, nb);

        // masked softmax in place
        softmax_rows<<<BSc, 256, 0, stream>>>(sc, mask, c0, S, S);

        // y[z] = relu(P_z @ v_z) : B^T = vT (batch cols z*S, ldb=BSc)
        gemm_bt<1, 0><<<4 * 8 * nb, 512, 0, stream>>>(
            sc, vT, y, S, S, BSc, D,
            (long long)S * S, (long long)S, (long long)S * D, 1.0f,
            4, 8, nb);

        // out_chunk = y @ woT^T   (fp32 output)
        gemm_bt<0, 1><<<4 * MTb, 512, 0, stream>>>(
            y, woT, out + (size_t)c0 * S * D, D, D, D, D, 0, 0, 0, 1.0f,
            4, MTb, 1);
    }
}

// Round 4
// 447.397 us; speedup vs baseline: 1.4232x; 1.0540x over previous
//
#include <hip/hip_runtime.h>
#include <stdint.h>
#include <stddef.h>

// ---------------------------------------------------------------------------
// Attention_7284264534326  (B=8, S=2048, D=1024). fp32 tensors, int32 mask,
// fp32 output.
//   q = (x1@wq)*D^-0.5 ; k = x2@wk ; v = x2@wv
//   a = softmax(q@k^T + mask*(-1e9)) ; y = relu(a@v) ; out = y@wo
// R10 == R9 resubmit (previous bench failed in the container infra, no
// kernel signal). R9 changes vs R8:
//   - mask*(-1e9) fused into the scores-GEMM epilogue (4 L2-hot int loads
//     per thread). Masked cols round to bf16(-1e9); exp underflows to 0.0f
//     exactly as before -> softmax denominators bit-identical.
//   - softmax rewritten wave-per-row: 32 elems/lane in registers, pure
//     shfl_xor reductions, no LDS / no barriers / no mask traffic.
// GEMM core (256^2 8-phase counted-vmcnt, 954-972 TF @K=1024) unchanged.
// ---------------------------------------------------------------------------

typedef __bf16 bf16x8 __attribute__((ext_vector_type(8)));
typedef float  floatx4 __attribute__((ext_vector_type(4)));

__device__ __forceinline__ unsigned short f2bf(float f) {
    unsigned u = __float_as_uint(f);
    return (unsigned short)((u + 0x7FFFu + ((u >> 16) & 1u)) >> 16);  // RNE
}
__device__ __forceinline__ float bf2f(unsigned short h) {
    return __uint_as_float(((unsigned)h) << 16);
}

__device__ __forceinline__ void async16(const void* g, void* l) {
    __builtin_amdgcn_global_load_lds(
        (const __attribute__((address_space(1))) unsigned int*)g,
        (__attribute__((address_space(3))) unsigned int*)l, 16, 0, 0);
}

// ---------------------------------------------------------------------------
// fp32 -> bf16, n % 2048 == 0.  blockIdx.y selects source {a,b}; dst is
// contiguous: out + y*n.
// ---------------------------------------------------------------------------
__global__ __launch_bounds__(256) void cvt_bf16_2(
    const float* __restrict__ a, const float* __restrict__ b,
    unsigned short* __restrict__ out, long long n)
{
    const float* in = blockIdx.y ? b : a;
    unsigned short* o = out + (size_t)blockIdx.y * n;
    long long i8 = ((long long)blockIdx.x * 256 + threadIdx.x) * 8;
    if (i8 >= n) return;
    float4 va = *(const float4*)(in + i8);
    float4 vb = *(const float4*)(in + i8 + 4);
    union { uint4 u; unsigned short h[8]; } ov;
    ov.h[0] = f2bf(va.x); ov.h[1] = f2bf(va.y); ov.h[2] = f2bf(va.z); ov.h[3] = f2bf(va.w);
    ov.h[4] = f2bf(vb.x); ov.h[5] = f2bf(vb.y); ov.h[6] = f2bf(vb.z); ov.h[7] = f2bf(vb.w);
    *(uint4*)(o + i8) = ov.u;
}

// ---------------------------------------------------------------------------
// fp32 [rows][cols] -> bf16 transposed out[c][r], 4 matrices (z-indexed).
// rows,cols % 32 == 0.  dsts contiguous at out + z*rows*cols.
// ---------------------------------------------------------------------------
__global__ __launch_bounds__(256) void cvt_transpose_w4(
    const float* __restrict__ w0, const float* __restrict__ w1,
    const float* __restrict__ w2, const float* __restrict__ w3,
    unsigned short* __restrict__ out, int rows, int cols)
{
    const int z = blockIdx.z;
    const float* in = (z == 0) ? w0 : (z == 1) ? w1 : (z == 2) ? w2 : w3;
    unsigned short* o = out + (size_t)z * rows * cols;

    __shared__ unsigned short tile[32][33];
    const int cbase = blockIdx.x * 32;
    const int rbase = blockIdx.y * 32;
#pragma unroll
    for (int i = 0; i < 4; i++) {
        int r = rbase + threadIdx.y + i * 8;
        tile[threadIdx.y + i * 8][threadIdx.x] =
            f2bf(in[(size_t)r * cols + (cbase + threadIdx.x)]);
    }
    __syncthreads();
#pragma unroll
    for (int i = 0; i < 4; i++) {
        int r = cbase + threadIdx.y + i * 8;
        o[(size_t)r * rows + (rbase + threadIdx.x)] =
            tile[threadIdx.x][threadIdx.y + i * 8];
    }
}

// ---------------------------------------------------------------------------
// C[m][n] = scale * sum_k A[m][k] * B[n][k]  (+ optional mask-add / relu).
// A,B bf16; C bf16 (F32OUT=0) or fp32 (F32OUT=1).
// 256x256 tile, BK=64, 512 threads (8 waves, 2Mx4N), 8-phase schedule
// (m194-m204 template). M,N % 256 == 0, K % 128 == 0.
// maskp != null: epilogue adds maskp[bz*ldc + col]*(-1e9) per output col.
// Block decode from local id:
//   gz>1 : bz = id%gz (batch->XCD), 4x4 supertiles (gx%4==0)
//   gz==1, gy%8==0: XCD m-banding; else plain row-major.
// Stage/read hazard ledger: see R7 header (unchanged).
// ---------------------------------------------------------------------------
#define MFMA16(a, b, c) __builtin_amdgcn_mfma_f32_16x16x32_bf16(a, b, c, 0, 0, 0)
#define BARF()  { __builtin_amdgcn_s_barrier(); asm volatile("" ::: "memory"); }
#define LGKM0() asm volatile("s_waitcnt lgkmcnt(0)" ::: "memory")
#define VMC(N)  asm volatile("s_waitcnt vmcnt(" #N ")" ::: "memory")

template <int RELU, int F32OUT>
__device__ __forceinline__ void gemm_core(
    const unsigned short* A, const unsigned short* B, void* Cv,
    int K, int lda, int ldb, int ldc,
    long long sA, long long sB, long long sC,
    float scale, int gx, int gy, int gz, int id, char* lds,
    const int* maskp)
{
    const int t    = threadIdx.x;
    const int wave = t >> 6;
    const int lane = t & 63;

    // ---- block swizzle ----
    int bz, bx, by;
    if (gz > 1) {
        bz = id % gz;                      // batch pinned to XCD (id%8)
        int tt  = id / gz;
        int stw = gx >> 2;
        int st  = tt >> 4, lt = tt & 15;   // 4x4 supertile
        bx = (st % stw) * 4 + (lt & 3);
        by = (st / stw) * 4 + (lt >> 2);
    } else if ((gy & 7) == 0) {
        bz = 0;
        int band = gy >> 3;
        int q = id >> 3, x7 = id & 7;      // XCD x7 gets contiguous m-band
        by = x7 * band + q / gx;
        bx = q % gx;
    } else {
        bz = 0; bx = id % gx; by = id / gx;
    }

    A += (long long)bz * sA;
    B += (long long)bz * sB;

    const int m0 = by * 256;
    const int n0 = bx * 256;
    const int wm = (wave >> 2) * 128;      // 2 M-waves
    const int wn = (wave & 3) * 64;        // 4 N-waves
    const int fr = lane & 15;
    const int fj = lane >> 4;

    // ---- fragment read addressing (byte offsets, XOR-swizzled slots) ----
    // lds regions (16384 B each): buf*65536 + {A0=0, A1=1, B0=2, B1=3}*16384
    // data (row r, 8-elem slot s) stored at slot s ^ (r&7)
    const int slotX0 = ((fj    ) ^ (fr & 7)) << 4;   // k-half 0
    const int slotX1 = ((fj + 4) ^ (fr & 7)) << 4;   // k-half 1
    const int aBase = (wm >> 7) * 16384 + fr * 128;
    const int bBase = 32768 + (wn >> 7) * 16384 + (wn & 64) * 128 + fr * 128;

    // ---- staging source (inverse swizzle; LDS dest is linear) ----
    const int off0 = wave * 1024 + lane * 16;            // issue-0 LDS offset
    const int r0   = off0 >> 7;                          // row 0..63
    const int c0   = (((off0 >> 4) & 7) ^ (r0 & 7)) << 3;// element col
    const unsigned short* Ag = A + (size_t)(m0 + r0) * lda + c0;
    const unsigned short* Bg = B + (size_t)(n0 + r0) * ldb + c0;
    char* ldsW = lds + wave * 1024;                      // wave-uniform base

#define STAGE_A(tile, h) { \
    const unsigned short* g_ = Ag + (size_t)((h) * 128) * lda + (tile) * 64; \
    char* d_ = ldsW + ((tile) & 1) * 65536 + (h) * 16384; \
    async16(g_, d_); \
    async16(g_ + (size_t)64 * lda, d_ + 8192); }
#define STAGE_B(tile, h) { \
    const unsigned short* g_ = Bg + (size_t)((h) * 128) * ldb + (tile) * 64; \
    char* d_ = ldsW + ((tile) & 1) * 65536 + 32768 + (h) * 16384; \
    async16(g_, d_); \
    async16(g_ + (size_t)64 * ldb, d_ + 8192); }

    bf16x8 af[2][2], bfv[4][2];
#define LOAD_B(buf) { \
    const char* p_ = lds + (buf) * 65536 + bBase; \
    bfv[0][0] = *(const bf16x8*)(p_ +    0 + slotX0); \
    bfv[0][1] = *(const bf16x8*)(p_ +    0 + slotX1); \
    bfv[1][0] = *(const bf16x8*)(p_ + 2048 + slotX0); \
    bfv[1][1] = *(const bf16x8*)(p_ + 2048 + slotX1); \
    bfv[2][0] = *(const bf16x8*)(p_ + 4096 + slotX0); \
    bfv[2][1] = *(const bf16x8*)(p_ + 4096 + slotX1); \
    bfv[3][0] = *(const bf16x8*)(p_ + 6144 + slotX0); \
    bfv[3][1] = *(const bf16x8*)(p_ + 6144 + slotX1); }
#define LOAD_A(buf, q) { \
    const char* p_ = lds + (buf) * 65536 + aBase + (q) * 4096; \
    af[0][0] = *(const bf16x8*)(p_ +    0 + slotX0); \
    af[0][1] = *(const bf16x8*)(p_ +    0 + slotX1); \
    af[1][0] = *(const bf16x8*)(p_ + 2048 + slotX0); \
    af[1][1] = *(const bf16x8*)(p_ + 2048 + slotX1); }
#define MFMAQ(q) { \
    __builtin_amdgcn_s_setprio(1); \
    acc[2*(q)  ][0] = MFMA16(af[0][0], bfv[0][0], acc[2*(q)  ][0]); \
    acc[2*(q)  ][0] = MFMA16(af[0][1], bfv[0][1], acc[2*(q)  ][0]); \
    acc[2*(q)  ][1] = MFMA16(af[0][0], bfv[1][0], acc[2*(q)  ][1]); \
    acc[2*(q)  ][1] = MFMA16(af[0][1], bfv[1][1], acc[2*(q)  ][1]); \
    acc[2*(q)  ][2] = MFMA16(af[0][0], bfv[2][0], acc[2*(q)  ][2]); \
    acc[2*(q)  ][2] = MFMA16(af[0][1], bfv[2][1], acc[2*(q)  ][2]); \
    acc[2*(q)  ][3] = MFMA16(af[0][0], bfv[3][0], acc[2*(q)  ][3]); \
    acc[2*(q)  ][3] = MFMA16(af[0][1], bfv[3][1], acc[2*(q)  ][3]); \
    acc[2*(q)+1][0] = MFMA16(af[1][0], bfv[0][0], acc[2*(q)+1][0]); \
    acc[2*(q)+1][0] = MFMA16(af[1][1], bfv[0][1], acc[2*(q)+1][0]); \
    acc[2*(q)+1][1] = MFMA16(af[1][0], bfv[1][0], acc[2*(q)+1][1]); \
    acc[2*(q)+1][1] = MFMA16(af[1][1], bfv[1][1], acc[2*(q)+1][1]); \
    acc[2*(q)+1][2] = MFMA16(af[1][0], bfv[2][0], acc[2*(q)+1][2]); \
    acc[2*(q)+1][2] = MFMA16(af[1][1], bfv[2][1], acc[2*(q)+1][2]); \
    acc[2*(q)+1][3] = MFMA16(af[1][0], bfv[3][0], acc[2*(q)+1][3]); \
    acc[2*(q)+1][3] = MFMA16(af[1][1], bfv[3][1], acc[2*(q)+1][3]); \
    __builtin_amdgcn_s_setprio(0); }

    floatx4 acc[8][4];
#pragma unroll
    for (int i = 0; i < 8; i++)
#pragma unroll
        for (int j = 0; j < 4; j++) acc[i][j] = floatx4{0.f, 0.f, 0.f, 0.f};

    // ---- prologue: tile0 full + tile1 B-halves (6 half-tiles, 12 loads) ----
    STAGE_A(0, 0); STAGE_A(0, 1); STAGE_B(0, 0); STAGE_B(0, 1);
    STAGE_B(1, 0); STAGE_B(1, 1);
    VMC(4);                                  // tile0 (oldest 8 loads) landed
    BARF();

    const int niter = K >> 7;                // 2 K-tiles (BK=64) per iter
    for (int it = 0; it < niter - 1; ++it) {
        const int T = 2 * it;
        // ---- tile T (buf0) ----
        LOAD_B(0); LOAD_A(0, 0); STAGE_A(T + 1, 0);
        BARF(); LGKM0(); MFMAQ(0); BARF();
        LOAD_A(0, 1); STAGE_A(T + 1, 1);
        BARF(); LGKM0(); MFMAQ(1); BARF();
        LOAD_A(0, 2); STAGE_B(T + 2, 0);
        BARF(); LGKM0(); MFMAQ(2); BARF();
        LOAD_A(0, 3); STAGE_B(T + 2, 1);
        BARF(); LGKM0(); MFMAQ(3); VMC(4); BARF();
        // ---- tile T+1 (buf1) ----
        LOAD_B(1); LOAD_A(1, 0); STAGE_A(T + 2, 0);
        BARF(); LGKM0(); MFMAQ(0); BARF();
        LOAD_A(1, 1); STAGE_A(T + 2, 1);
        BARF(); LGKM0(); MFMAQ(1); BARF();
        LOAD_A(1, 2); STAGE_B(T + 3, 0);
        BARF(); LGKM0(); MFMAQ(2); BARF();
        LOAD_A(1, 3); STAGE_B(T + 3, 1);
        BARF(); LGKM0(); MFMAQ(3); VMC(4); BARF();
    }
    {   // ---- peeled final iteration (no T+2/T+3; drain) ----
        const int T = 2 * (niter - 1);
        LOAD_B(0); LOAD_A(0, 0); STAGE_A(T + 1, 0);
        BARF(); LGKM0(); MFMAQ(0); BARF();
        LOAD_A(0, 1); STAGE_A(T + 1, 1);
        BARF(); LGKM0(); MFMAQ(1); BARF();
        LOAD_A(0, 2);
        BARF(); LGKM0(); MFMAQ(2); BARF();
        LOAD_A(0, 3);
        BARF(); LGKM0(); MFMAQ(3); VMC(0); BARF();
        LOAD_B(1); LOAD_A(1, 0);
        BARF(); LGKM0(); MFMAQ(0); BARF();
        LOAD_A(1, 1);
        BARF(); LGKM0(); MFMAQ(1); BARF();
        LOAD_A(1, 2);
        BARF(); LGKM0(); MFMAQ(2); BARF();
        LOAD_A(1, 3);
        BARF(); LGKM0(); MFMAQ(3); BARF();
    }

    // C/D layout (m89-verified): col = lane&15, row = (lane>>4)*4 + r
    const int er = (lane >> 4) * 4;
    const int ec = lane & 15;

    // optional mask-add: mask value depends only on output column + batch
    float madd[4];
    if (maskp) {
        const int* mrow = maskp + (size_t)bz * ldc;
#pragma unroll
        for (int j = 0; j < 4; j++)
            madd[j] = (float)mrow[n0 + wn + j * 16 + ec] * (-1.0e9f);
    } else {
        madd[0] = madd[1] = madd[2] = madd[3] = 0.f;
    }

    if (F32OUT) {
        float* C = (float*)Cv + (long long)bz * sC;
#pragma unroll
        for (int i = 0; i < 8; i++)
#pragma unroll
            for (int j = 0; j < 4; j++)
#pragma unroll
                for (int r = 0; r < 4; r++) {
                    float v = acc[i][j][r] * scale + madd[j];
                    if (RELU) v = fmaxf(v, 0.f);
                    C[(size_t)(m0 + wm + i * 16 + er + r) * ldc
                      + (n0 + wn + j * 16 + ec)] = v;
                }
    } else {
        unsigned short* C = (unsigned short*)Cv + (long long)bz * sC;
#pragma unroll
        for (int i = 0; i < 8; i++)
#pragma unroll
            for (int j = 0; j < 4; j++)
#pragma unroll
                for (int r = 0; r < 4; r++) {
                    float v = acc[i][j][r] * scale + madd[j];
                    if (RELU) v = fmaxf(v, 0.f);
                    C[(size_t)(m0 + wm + i * 16 + er + r) * ldc
                      + (n0 + wn + j * 16 + ec)] = f2bf(v);
                }
    }
#undef STAGE_A
#undef STAGE_B
#undef LOAD_A
#undef LOAD_B
#undef MFMAQ
}

template <int RELU, int F32OUT>
__global__ __launch_bounds__(512, 2) void gemm_bt(
    const unsigned short* __restrict__ A,
    const unsigned short* __restrict__ B,
    void* __restrict__ Cv,
    int K, int lda, int ldb, int ldc,
    long long sA, long long sB, long long sC,
    float scale, int gx, int gy, int gz,
    const int* __restrict__ maskp)
{
    __shared__ __align__(16) char lds[131072];
    gemm_core<RELU, F32OUT>(A, B, Cv, K, lda, ldb, ldc, sA, sB, sC,
                            scale, gx, gy, gz, blockIdx.x, lds, maskp);
}

// ---- 3-problem merged GEMM (independent problems, one dispatch) ----------
struct GemmDesc {
    const unsigned short* A;
    const unsigned short* B;
    void* C;
    int K, lda, ldb, ldc;
    long long sA, sB, sC;
    float scale;
    int gx, gy, gz, nblk;
};
struct GemmDesc3 { GemmDesc d[3]; };

__global__ __launch_bounds__(512, 2) void gemm_bt3(GemmDesc3 dd)
{
    __shared__ __align__(16) char lds[131072];
    int id = blockIdx.x;
    GemmDesc g = dd.d[0];
    if (id >= g.nblk) {
        id -= g.nblk; g = dd.d[1];
        if (id >= g.nblk) { id -= g.nblk; g = dd.d[2]; }
    }
    gemm_core<0, 0>(g.A, g.B, g.C, g.K, g.lda, g.ldb, g.ldc,
                    g.sA, g.sB, g.sC, g.scale, g.gx, g.gy, g.gz, id, lds,
                    nullptr);
}

// ---------------------------------------------------------------------------
// In-place softmax over bf16 rows (len Sk), fp32 math.  Wave-per-row:
// 4 waves/block, 32 elems/lane in registers, shfl_xor reductions only.
// Mask already folded into the scores (epilogue of the scores GEMM).
// ---------------------------------------------------------------------------
__global__ __launch_bounds__(256) void softmax_rows_w(
    unsigned short* __restrict__ S, int Sk)
{
    const int wave = threadIdx.x >> 6;
    const int lane = threadIdx.x & 63;
    const int row  = blockIdx.x * 4 + wave;
    unsigned short* p = S + (size_t)row * Sk;

    union { uint4 u; unsigned short h[8]; } lu[4];
#pragma unroll
    for (int i = 0; i < 4; i++)
        lu[i].u = *(const uint4*)(p + i * 512 + lane * 8);

    float v[32];
    float mx = -3.0e38f;
#pragma unroll
    for (int i = 0; i < 4; i++)
#pragma unroll
        for (int j = 0; j < 8; j++) {
            v[i * 8 + j] = bf2f(lu[i].h[j]);
            mx = fmaxf(mx, v[i * 8 + j]);
        }
#pragma unroll
    for (int o = 32; o > 0; o >>= 1) mx = fmaxf(mx, __shfl_xor(mx, o));

    float sum = 0.f;
#pragma unroll
    for (int e = 0; e < 32; e++) { v[e] = __expf(v[e] - mx); sum += v[e]; }
#pragma unroll
    for (int o = 32; o > 0; o >>= 1) sum += __shfl_xor(sum, o);

    const float inv = 1.0f / sum;
#pragma unroll
    for (int i = 0; i < 4; i++) {
#pragma unroll
        for (int j = 0; j < 8; j++) lu[i].h[j] = f2bf(v[i * 8 + j] * inv);
        *(uint4*)(p + i * 512 + lane * 8) = lu[i].u;
    }
}

// Diagnostic: future failure with absmax ~1.3 => "ws too small" branch fired.
__global__ void fill_one_f32(float* o, int n) {
    int i = blockIdx.x * 256 + threadIdx.x;
    if (i < n) o[i] = 1.0f;
}

// ---------------------------------------------------------------------------
extern "C" void kernel_launch(void* const* d_in, const int* in_sizes, int n_in,
                              void* d_out, int out_size, void* d_ws, size_t ws_size,
                              hipStream_t stream)
{
    const float* x1   = (const float*)d_in[0];
    const float* x2   = (const float*)d_in[1];
    const int*   mask = (const int*)d_in[2];
    const float* wq   = (const float*)d_in[3];
    const float* wk   = (const float*)d_in[4];
    const float* wv   = (const float*)d_in[5];
    const float* wo   = (const float*)d_in[6];
    float*       out  = (float*)d_out;

    const int S = 2048, D = 1024, Btot = 8;

    // ws bf16 elems = 4*D*D + nb*(5*S*D + S*S):  8MB + nb*28MB bytes
    const size_t WT = (size_t)4 * D * D;
    const size_t PB = (size_t)5 * S * D + (size_t)S * S;
    const size_t avail = ws_size / 2;
    int nb = 0;
    if      (WT + 8 * PB <= avail) nb = 8;
    else if (WT + 4 * PB <= avail) nb = 4;
    else if (WT + 2 * PB <= avail) nb = 2;
    else if (WT + 1 * PB <= avail) nb = 1;
    if (nb == 0) {
        fill_one_f32<<<(out_size + 255) / 256, 256, 0, stream>>>(out, out_size);
        return;
    }

    unsigned short* wqT = (unsigned short*)d_ws;
    unsigned short* wkT = wqT + (size_t)D * D;
    unsigned short* wvT = wkT + (size_t)D * D;
    unsigned short* woT = wvT + (size_t)D * D;
    unsigned short* x1b = woT + (size_t)D * D;              // nb*S x D  bf16
    unsigned short* x2b = x1b + (size_t)nb * S * D;         // nb*S x D
    unsigned short* q   = x2b + (size_t)nb * S * D;         // nb*S x D
    unsigned short* kk  = q   + (size_t)nb * S * D;         // nb*S x D
    unsigned short* vT  = kk  + (size_t)nb * S * D;         // D x nb*S
    unsigned short* sc  = vT  + (size_t)nb * S * D;         // nb x S x S
    unsigned short* y   = q;                                // alias (q dead)

    // all 4 weight transposes in one launch (dsts contiguous from wqT)
    cvt_transpose_w4<<<dim3(32, 32, 4), dim3(32, 8), 0, stream>>>(
        wq, wk, wv, wo, wqT, D, D);

    const int BSc = nb * S;                                 // rows per chunk
    const int MTb = BSc / 256;                              // 256-wide m-tiles
    const long long NE = (long long)BSc * D;                // elems per chunk
    for (int c0 = 0; c0 < Btot; c0 += nb) {
        const float* x1c = x1 + (size_t)c0 * S * D;
        const float* x2c = x2 + (size_t)c0 * S * D;

        // both converts in one launch (x1b,x2b contiguous)
        cvt_bf16_2<<<dim3((unsigned)(NE / 2048), 2), 256, 0, stream>>>(
            x1c, x2c, x1b, NE);

        // q/k/vT projections: 3 independent problems, one dispatch
        GemmDesc3 dd;
        // q = x1b @ wqT^T * D^-0.5
        dd.d[0] = {x1b, wqT, q, D, D, D, D, 0, 0, 0, 0.03125f, 4, MTb, 1, 4 * MTb};
        // k = x2b @ wkT^T
        dd.d[1] = {x2b, wkT, kk, D, D, D, D, 0, 0, 0, 1.0f, 4, MTb, 1, 4 * MTb};
        // vT[e][s] = sum_d wvT[e][d] * x2b[s][d]   (D x BSc)
        dd.d[2] = {wvT, x2b, vT, D, D, D, BSc, 0, 0, 0, 1.0f, MTb, 4, 1, MTb * 4};
        gemm_bt3<<<12 * MTb, 512, 0, stream>>>(dd);

        // scores[z] = q_z @ k_z^T + mask*(-1e9)   (gx=8, gy=8, gz=nb)
        gemm_bt<0, 0><<<8 * 8 * nb, 512, 0, stream>>>(
            q, kk, sc, D, D, D, S,
            (long long)S * D, (long long)S * D, (long long)S * S, 1.0f,
            8, 8, nb, mask + (size_t)c0 * S);

        // softmax in place (mask already applied)
        softmax_rows_w<<<BSc / 4, 256, 0, stream>>>(sc, S);

        // y[z] = relu(P_z @ v_z) : B^T = vT (batch cols z*S, ldb=BSc)
        gemm_bt<1, 0><<<4 * 8 * nb, 512, 0, stream>>>(
            sc, vT, y, S, S, BSc, D,
            (long long)S * S, (long long)S, (long long)S * D, 1.0f,
            4, 8, nb, nullptr);

        // out_chunk = y @ woT^T   (fp32 output)
        gemm_bt<0, 1><<<4 * MTb, 512, 0, stream>>>(
            y, woT, out + (size_t)c0 * S * D, D, D, D, D, 0, 0, 0, 1.0f,
            4, MTb, 1, nullptr);
    }
}